// Round 14
// baseline (260.773 us; speedup 1.0000x reference)
//
#include <hip/hip_runtime.h>

#define B_  4
#define S_  2048
#define D_  1024
#define H_  16
#define HD_ 64
#define BS_ (B_*S_)   // 8192

typedef _Float16 f16;
typedef _Float16 f16_8 __attribute__((ext_vector_type(8)));
typedef _Float16 f16_4 __attribute__((ext_vector_type(4)));
typedef float    f32_4 __attribute__((ext_vector_type(4)));
typedef unsigned int u32;

#define MFMA32(a,b,c) __builtin_amdgcn_mfma_f32_16x16x32_f16(a, b, c, 0, 0, 0)
#define MFMA16(a,b,c) __builtin_amdgcn_mfma_f32_16x16x16f16(a, b, c, 0, 0, 0)
#define NEG_INF (-__builtin_inff())

// async global->LDS, 16B per lane. chunk_base in lane units (16B each),
// must be wave-uniform; HW adds lane*16B.
__device__ inline void gl_lds16(const f16* g, f16* lds_base, int chunk_base) {
    __builtin_amdgcn_global_load_lds(
        (const __attribute__((address_space(1))) u32*)g,
        (__attribute__((address_space(3))) u32*)(lds_base + (size_t)chunk_base * 8),
        16, 0, 0);
}

// ---------------------------------------------------------------------------
// prep: blocks [0,4096) convert X fp32->f16; blocks [4096,4864) transpose
// W_attn fp32 [1024][3072] -> Wta f16 [3072][1024]; blocks [4864,5120)
// (big-ws mode only) transpose W_proj -> Wtp.
// ---------------------------------------------------------------------------
__global__ __launch_bounds__(256) void prep(
    const float* __restrict__ X,  f16* __restrict__ Xh,
    const float* __restrict__ Wa, f16* __restrict__ Wta,
    const float* __restrict__ Wp, f16* __restrict__ Wtp)
{
    __shared__ f16 T[64][72];
    const int t = threadIdx.x;
    const int bid = blockIdx.x;
    if (bid < 4096) {
        const size_t i = ((size_t)bid * 256 + t) * 8;
        float4 a = *(const float4*)&X[i];
        float4 b = *(const float4*)&X[i + 4];
        f16 h[8] = {(f16)a.x,(f16)a.y,(f16)a.z,(f16)a.w,
                    (f16)b.x,(f16)b.y,(f16)b.z,(f16)b.w};
        *(uint4*)&Xh[i] = *(const uint4*)h;
        return;
    }
    int n0, k0, ncols;
    const float* Wsrc;
    f16* Wdst;
    if (bid < 4864) {
        const int idx = bid - 4096;
        n0 = (idx % 48) * 64; k0 = (idx / 48) * 64;
        ncols = 3072; Wsrc = Wa; Wdst = Wta;
    } else {
        const int idx = bid - 4864;
        n0 = (idx % 16) * 64; k0 = (idx / 16) * 64;
        ncols = 1024; Wsrc = Wp; Wdst = Wtp;
    }
    const int nl4 = (t & 15) * 4;
    #pragma unroll
    for (int r = 0; r < 4; r++) {
        const int kl = (t >> 4) + r * 16;
        float4 v = *(const float4*)&Wsrc[(size_t)(k0 + kl) * ncols + n0 + nl4];
        T[nl4 + 0][kl] = (f16)v.x;
        T[nl4 + 1][kl] = (f16)v.y;
        T[nl4 + 2][kl] = (f16)v.z;
        T[nl4 + 3][kl] = (f16)v.w;
    }
    __syncthreads();
    const int nr = t >> 2, kc = (t & 3) * 16;
    *(uint4*)&Wdst[(size_t)(n0 + nr) * 1024 + k0 + kc]     = *(uint4*)&T[nr][kc];
    *(uint4*)&Wdst[(size_t)(n0 + nr) * 1024 + k0 + kc + 8] = *(uint4*)&T[nr][kc + 8];
}

// ---------------------------------------------------------------------------
// Transpose + convert: W [1024][ncols] fp32 -> Wt [ncols][1024] f16
// (fallback path only: runs after attn, Wtp aliases the dead Q buffer)
// ---------------------------------------------------------------------------
__global__ __launch_bounds__(256) void trans_w(
    const float* __restrict__ W, f16* __restrict__ Wt, int ncols)
{
    __shared__ f16 T[64][72];
    const int t = threadIdx.x;
    const int n0 = blockIdx.x * 64, k0 = blockIdx.y * 64;
    const int nl4 = (t & 15) * 4;
    #pragma unroll
    for (int r = 0; r < 4; r++) {
        const int kl = (t >> 4) + r * 16;
        float4 v = *(const float4*)&W[(size_t)(k0 + kl) * ncols + n0 + nl4];
        T[nl4 + 0][kl] = (f16)v.x;
        T[nl4 + 1][kl] = (f16)v.y;
        T[nl4 + 2][kl] = (f16)v.z;
        T[nl4 + 3][kl] = (f16)v.w;
    }
    __syncthreads();
    const int nr = t >> 2, kc = (t & 3) * 16;
    *(uint4*)&Wt[(size_t)(n0 + nr) * 1024 + k0 + kc]     = *(uint4*)&T[nr][kc];
    *(uint4*)&Wt[(size_t)(n0 + nr) * 1024 + k0 + kc + 8] = *(uint4*)&T[nr][kc + 8];
}

// ---------------------------------------------------------------------------
// GEMM1: qkv = x @ W_attn + b_attn.  Deep-pipeline K-loop (validated
// r5/r10); r11 coalesced Q/K epilogue (validated r12: left top-5).
// ---------------------------------------------------------------------------
__global__ __launch_bounds__(512, 2) void qkv_gemm(
    const f16*   __restrict__ Xh,    // [8192,1024] f16
    const f16*   __restrict__ Wta,   // [3072,1024] f16 (pre-transposed)
    const float* __restrict__ bias,  // [3072]
    f16* __restrict__ Qb, f16* __restrict__ Kb, f16* __restrict__ Vt)
{
    __shared__ f16 lds[73728];   // 3 x (A 8192 + B 16384) f16 = 144 KB

    const int t    = threadIdx.x;
    const int lane = t & 63;
    const int w    = t >> 6;                 // 0..7
    const int quad = lane >> 4, l15 = lane & 15;
    const int wr = w >> 2, wc = w & 3;       // 2 x 4 wave grid
    const int m0 = blockIdx.x * 128;         // m fastest -> X strips XCD-local
    const int n0 = blockIdx.y * 256;
    const int wb = t & 448;                  // wave-uniform chunk base

    int aoff[2], boff[4];
    #pragma unroll
    for (int c = 0; c < 2; c++) {
        const int i = c*512 + t, row = i >> 3, sl = i & 7;
        aoff[c] = row*1024 + ((sl ^ (row & 7)) << 3);
    }
    #pragma unroll
    for (int c = 0; c < 4; c++) {
        const int i = c*512 + t, row = i >> 3, sl = i & 7;
        boff[c] = row*1024 + ((sl ^ (row & 7)) << 3);
    }
    int fa[4][2], fb[4][2];
    #pragma unroll
    for (int mi = 0; mi < 4; mi++)
        #pragma unroll
        for (int kk = 0; kk < 2; kk++)
            fa[mi][kk] = (wr*64 + mi*16 + l15)*64 + (((kk*4 + quad) ^ (l15 & 7)) << 3);
    #pragma unroll
    for (int ni = 0; ni < 4; ni++)
        #pragma unroll
        for (int kk = 0; kk < 2; kk++)
            fb[ni][kk] = (wc*64 + ni*16 + l15)*64 + (((kk*4 + quad) ^ (l15 & 7)) << 3);

    const f16* Ag = Xh  + (size_t)m0 * 1024;
    const f16* Bg = Wta + (size_t)n0 * 1024;

    f32_4 acc[4][4] = {};

    #pragma unroll
    for (int c = 0; c < 2; c++) gl_lds16(Ag + aoff[c],       lds,                c*512 + wb);
    #pragma unroll
    for (int c = 0; c < 4; c++) gl_lds16(Bg + boff[c],       lds + 8192,         c*512 + wb);
    #pragma unroll
    for (int c = 0; c < 2; c++) gl_lds16(Ag + 64 + aoff[c],  lds + 24576,        c*512 + wb);
    #pragma unroll
    for (int c = 0; c < 4; c++) gl_lds16(Bg + 64 + boff[c],  lds + 24576 + 8192, c*512 + wb);
    asm volatile("s_waitcnt vmcnt(6)" ::: "memory");
    __builtin_amdgcn_s_barrier();
    asm volatile("" ::: "memory");

    int cur = 0;
    #pragma unroll 1
    for (int T = 0; T < 16; T++) {
        f16* buf        = lds + cur*24576;
        const int nxt   = cur ? cur - 1 : 2;
        f16* nbuf       = lds + nxt*24576;
        const bool st   = (T < 14);
        const int  kt2  = (T + 2) * 64;

        if (st) {
            #pragma unroll
            for (int c = 0; c < 2; c++)
                gl_lds16(Ag + kt2 + aoff[c], nbuf, c*512 + wb);
        }
        f16_8 af[4][2], bf[2][2];
        #pragma unroll
        for (int mi = 0; mi < 4; mi++)
            #pragma unroll
            for (int kk = 0; kk < 2; kk++)
                af[mi][kk] = *(const f16_8*)&buf[fa[mi][kk]];
        #pragma unroll
        for (int ni = 0; ni < 2; ni++)
            #pragma unroll
            for (int kk = 0; kk < 2; kk++)
                bf[ni][kk] = *(const f16_8*)&buf[8192 + fb[ni][kk]];
        asm volatile("" ::: "memory");
        __builtin_amdgcn_s_barrier();
        asm volatile("" ::: "memory");
        __builtin_amdgcn_s_setprio(1);
        #pragma unroll
        for (int kk = 0; kk < 2; kk++)
            #pragma unroll
            for (int mi = 0; mi < 4; mi++)
                #pragma unroll
                for (int ni = 0; ni < 2; ni++)
                    acc[mi][ni] = MFMA32(af[mi][kk], bf[ni][kk], acc[mi][ni]);
        __builtin_amdgcn_s_setprio(0);
        asm volatile("" ::: "memory");
        __builtin_amdgcn_s_barrier();
        asm volatile("" ::: "memory");

        if (st) {
            #pragma unroll
            for (int c = 0; c < 4; c++)
                gl_lds16(Bg + kt2 + boff[c], nbuf + 8192, c*512 + wb);
        }
        #pragma unroll
        for (int ni = 0; ni < 2; ni++)
            #pragma unroll
            for (int kk = 0; kk < 2; kk++)
                bf[ni][kk] = *(const f16_8*)&buf[8192 + fb[2 + ni][kk]];
        asm volatile("" ::: "memory");
        __builtin_amdgcn_s_barrier();
        asm volatile("" ::: "memory");
        __builtin_amdgcn_s_setprio(1);
        #pragma unroll
        for (int kk = 0; kk < 2; kk++)
            #pragma unroll
            for (int mi = 0; mi < 4; mi++)
                #pragma unroll
                for (int ni = 0; ni < 2; ni++)
                    acc[mi][2 + ni] = MFMA32(af[mi][kk], bf[ni][kk], acc[mi][2 + ni]);
        __builtin_amdgcn_s_setprio(0);
        if (T < 14)       asm volatile("s_waitcnt vmcnt(6)" ::: "memory");
        else if (T == 14) asm volatile("s_waitcnt vmcnt(0)" ::: "memory");
        __builtin_amdgcn_s_barrier();
        asm volatile("" ::: "memory");

        cur = (cur >= 2) ? 0 : cur + 1;
    }

    const int which = n0 >> 10;      // 0=Q 1=K 2=V
    float bcol[4];
    #pragma unroll
    for (int ni = 0; ni < 4; ni++)
        bcol[ni] = bias[n0 + wc*64 + ni*16 + l15];

    if (which < 2) {
        f16* dstB = (which == 0) ? Qb : Kb;
        const float sc = (which == 0) ? 0.125f * 1.44269504f : 1.0f;
        f16* Ct2 = lds;              // [128][264] f16 = 67.6 KB, buffers dead
        #pragma unroll
        for (int mi = 0; mi < 4; mi++)
        #pragma unroll
        for (int ni = 0; ni < 4; ni++)
        #pragma unroll
        for (int r = 0; r < 4; r++) {
            int ml = wr*64 + mi*16 + quad*4 + r;
            int nl = wc*64 + ni*16 + l15;
            Ct2[ml*264 + nl] = (f16)((acc[mi][ni][r] + bcol[ni]) * sc);
        }
        __syncthreads();
        const int b  = m0 >> 11, s0 = m0 & 2047;
        const int h0 = (n0 & 1023) >> 6;
        #pragma unroll
        for (int c = 0; c < 8; c++) {
            const int i   = c*512 + t;
            const int row = i >> 5, j = (i >> 3) & 3, k = i & 7;
            f16* dst = dstB + ((size_t)(b*16 + h0 + j)*2048 + s0 + row)*64 + k*8;
            *(uint4*)dst = *(const uint4*)&Ct2[row*264 + j*64 + k*8];
        }
    } else {
        f16* Ct = lds;               // [256][136] f16, buffers dead
        #pragma unroll
        for (int mi = 0; mi < 4; mi++)
        #pragma unroll
        for (int ni = 0; ni < 4; ni++)
        #pragma unroll
        for (int r = 0; r < 4; r++) {
            int nl = wc*64 + ni*16 + l15;
            int ml = wr*64 + mi*16 + quad*4 + r;
            Ct[nl*136 + ml] = (f16)(acc[mi][ni][r] + bcol[ni]);
        }
        __syncthreads();
        const int row = t >> 1, half = t & 1;
        const int nv = (n0 & 1023) + row;
        const int h = nv >> 6, hd = nv & 63;
        const int b = m0 >> 11;
        const int s0 = (m0 & 2047) + half*64;
        f16* dst = Vt + ((size_t)(b*16 + h)*64 + hd)*2048 + s0;
        #pragma unroll
        for (int j = 0; j < 8; j++)
            *(uint4*)&dst[j*8] = *(uint4*)&Ct[row*136 + half*64 + j*8];
    }
}

// ---------------------------------------------------------------------------
// Flash causal attention.  r13: 3-deep LDS ring (48 KB) with counted
// vmcnt(8) steady-state guard -> issue-to-use distance = 2 tile intervals
// (r12's depth-1 vmcnt(4) exposed L2/HBM latency every tile on the long
// strips, the kernel's makespan).  Everything else r10/r12-validated:
// one strip per block (4 waves), grid (64,16) longest-first, XOR swizzle,
// setprio.
// ---------------------------------------------------------------------------
__global__ __launch_bounds__(256, 4) void attn(
    const f16* __restrict__ Qb,
    const f16* __restrict__ Kb,
    const f16* __restrict__ Vt,     // [bh][hd][s]
    f16* __restrict__ Y)            // [8192,1024]
{
    __shared__ f16 lds[24576];      // 3 buf x (K[64][64] + V[64][64]) = 48 KB

    const int t    = threadIdx.x;
    const int w    = t >> 6;        // 0..3
    const int lane = t & 63;
    const int quad = lane >> 4, l15 = lane & 15;
    const int bh   = blockIdx.x;    // bh fastest -> same XCD per bh
    const int b    = bh >> 4, h = bh & 15;
    const int strip = 15 - (int)blockIdx.y;   // longest first
    const int qw   = strip*128 + w*32;
    const int NT   = 2*strip + 2;

    const f16* qh = Qb + (size_t)bh * S_ * 64;
    const f16* kh = Kb + (size_t)bh * S_ * 64;
    const f16* vt = Vt + (size_t)bh * 64 * S_;

    int srcK[2], srcV[2];
    #pragma unroll
    for (int c = 0; c < 2; c++) {
        const int i = c*256 + t, row = i >> 3, sl = i & 7;
        const int sw = ((sl ^ (row & 7)) << 3);
        srcK[c] = row*64   + sw;
        srcV[c] = row*2048 + sw;
    }
    const int wbase = t & 192;      // wave-uniform dest base
    const int l7    = l15 & 7;
    const f16_4 ones = {(f16)1,(f16)1,(f16)1,(f16)1};

    f16_8 qa[2][2];
    #pragma unroll
    for (int rt = 0; rt < 2; rt++)
        #pragma unroll
        for (int c = 0; c < 2; c++)
            qa[rt][c] = *(const f16_8*)&qh[(size_t)(qw + rt*16 + l15)*64 + c*32 + quad*8];

    f32_4 o[2][4] = {};
    f32_4 lacc[2] = {};

    // prologue: stage tiles 0 and 1 (NT is always >= 2)
    #pragma unroll
    for (int c = 0; c < 2; c++) {
        gl_lds16(kh + srcK[c], lds,        c*256 + wbase);
        gl_lds16(vt + srcV[c], lds + 4096, c*256 + wbase);
    }
    #pragma unroll
    for (int c = 0; c < 2; c++) {
        gl_lds16(kh + 64*64 + srcK[c], lds + 8192,        c*256 + wbase);
        gl_lds16(vt + 64    + srcV[c], lds + 8192 + 4096, c*256 + wbase);
    }

    #pragma unroll 1
    for (int kt = 0; kt < NT; kt++) {
        const int kbase = kt * 64;
        f16* Ks = lds + (kt % 3) * 8192;
        f16* Vs = Ks + 4096;

        if (kt + 2 < NT) {
            const int nb = kbase + 128;
            f16* nK = lds + ((kt + 2) % 3) * 8192;
            #pragma unroll
            for (int c = 0; c < 2; c++) {
                gl_lds16(kh + (size_t)nb*64 + srcK[c], nK,        c*256 + wbase);
                gl_lds16(vt + nb + srcV[c],            nK + 4096, c*256 + wbase);
            }
            asm volatile("s_waitcnt vmcnt(8)" ::: "memory");
        } else if (kt + 1 < NT) {
            asm volatile("s_waitcnt vmcnt(4)" ::: "memory");
        } else {
            asm volatile("s_waitcnt vmcnt(0)" ::: "memory");
        }
        __builtin_amdgcn_s_barrier();
        asm volatile("" ::: "memory");

        if (kbase <= qw + 31) {      // wave-uniform
            f16_8 kb[4][2];
            #pragma unroll
            for (int sub = 0; sub < 4; sub++)
                #pragma unroll
                for (int c = 0; c < 2; c++)
                    kb[sub][c] = *(const f16_8*)
                        &Ks[(sub*16 + l15)*64 + (((c*4 + quad) ^ l7) << 3)];
            f32_4 st[2][4];
            __builtin_amdgcn_s_setprio(1);
            #pragma unroll
            for (int rt = 0; rt < 2; rt++)
                #pragma unroll
                for (int sub = 0; sub < 4; sub++) {
                    f32_4 a = {};
                    a = MFMA32(kb[sub][0], qa[rt][0], a);
                    a = MFMA32(kb[sub][1], qa[rt][1], a);
                    st[rt][sub] = a;
                }
            __builtin_amdgcn_s_setprio(0);

            const bool masked = (kbase + 63 > qw);
            f16_4 pt[2][4];
            #pragma unroll
            for (int rt = 0; rt < 2; rt++)
            #pragma unroll
            for (int sub = 0; sub < 4; sub++) {
                const int qrow = qw + rt*16 + l15;
                f16_4 p;
                #pragma unroll
                for (int r = 0; r < 4; r++) {
                    float x = st[rt][sub][r];
                    if (masked) {
                        int key = kbase + sub*16 + quad*4 + r;
                        x = (key <= qrow) ? x : NEG_INF;
                    }
                    p[r] = (f16)__builtin_amdgcn_exp2f(x);
                }
                pt[rt][sub] = p;
            }

            #pragma unroll
            for (int rt = 0; rt < 2; rt++) {
                f16_4 ps = (pt[rt][0] + pt[rt][1]) + (pt[rt][2] + pt[rt][3]);
                lacc[rt] = MFMA16(ps, ones, lacc[rt]);
            }

            __builtin_amdgcn_s_setprio(1);
            #pragma unroll
            for (int sub = 0; sub < 4; sub++) {
                f16_4 vb[4];
                #pragma unroll
                for (int tt = 0; tt < 4; tt++)
                    vb[tt] = *(const f16_4*)
                        &Vs[(tt*16 + l15)*64 +
                            ((((sub*2 + (quad >> 1)) ^ l7) << 3) + (quad & 1)*4)];
                #pragma unroll
                for (int rt = 0; rt < 2; rt++)
                    #pragma unroll
                    for (int tt = 0; tt < 4; tt++)
                        o[rt][tt] = MFMA16(pt[rt][sub], vb[tt], o[rt][tt]);
            }
            __builtin_amdgcn_s_setprio(0);
        }
        asm volatile("" ::: "memory");
        __builtin_amdgcn_s_barrier();
        asm volatile("" ::: "memory");
    }

    #pragma unroll
    for (int rt = 0; rt < 2; rt++)
    #pragma unroll
    for (int r = 0; r < 4; r++) {
        float inv = 1.0f / lacc[rt][r];
        int srw = qw + rt*16 + quad*4 + r;
        #pragma unroll
        for (int tt = 0; tt < 4; tt++)
            Y[(size_t)(b*S_ + srw)*1024 + h*64 + tt*16 + l15] =
                (f16)(o[rt][tt][r] * inv);
    }
}

// ---------------------------------------------------------------------------
// GEMM2: out = y @ W_proj + b_proj.  r11-validated qkv K-loop clone.
// Grid (64,4) = 256 blocks = exactly 1/CU.
// ---------------------------------------------------------------------------
__global__ __launch_bounds__(512, 2) void proj_gemm(
    const f16* __restrict__ Yb,     // [8192,1024]
    const f16* __restrict__ Wtp,    // [1024,1024] (pre-transposed)
    const float* __restrict__ bias, // [1024]
    float* __restrict__ Out)        // [8192,1024] fp32
{
    __shared__ f16 lds[73728];   // 144 KB

    const int t    = threadIdx.x;
    const int lane = t & 63;
    const int w    = t >> 6;
    const int quad = lane >> 4, l15 = lane & 15;
    const int wr = w >> 2, wc = w & 3;
    const int m0 = blockIdx.x * 128;
    const int n0 = blockIdx.y * 256;
    const int wb = t & 448;

    int aoff[2], boff[4];
    #pragma unroll
    for (int c = 0; c < 2; c++) {
        const int i = c*512 + t, row = i >> 3, sl = i & 7;
        aoff[c] = row*1024 + ((sl ^ (row & 7)) << 3);
    }
    #pragma unroll
    for (int c = 0; c < 4; c++) {
        const int i = c*512 + t, row = i >> 3, sl = i & 7;
        boff[c] = row*1024 + ((sl ^ (row & 7)) << 3);
    }
    int fa[4][2], fb[4][2];
    #pragma unroll
    for (int mi = 0; mi < 4; mi++)
        #pragma unroll
        for (int kk = 0; kk < 2; kk++)
            fa[mi][kk] = (wr*64 + mi*16 + l15)*64 + (((kk*4 + quad) ^ (l15 & 7)) << 3);
    #pragma unroll
    for (int ni = 0; ni < 4; ni++)
        #pragma unroll
        for (int kk = 0; kk < 2; kk++)
            fb[ni][kk] = (wc*64 + ni*16 + l15)*64 + (((kk*4 + quad) ^ (l15 & 7)) << 3);

    const f16* Ag = Yb  + (size_t)m0 * 1024;
    const f16* Bg = Wtp + (size_t)n0 * 1024;

    f32_4 acc[4][4] = {};

    #pragma unroll
    for (int c = 0; c < 2; c++) gl_lds16(Ag + aoff[c],       lds,                c*512 + wb);
    #pragma unroll
    for (int c = 0; c < 4; c++) gl_lds16(Bg + boff[c],       lds + 8192,         c*512 + wb);
    #pragma unroll
    for (int c = 0; c < 2; c++) gl_lds16(Ag + 64 + aoff[c],  lds + 24576,        c*512 + wb);
    #pragma unroll
    for (int c = 0; c < 4; c++) gl_lds16(Bg + 64 + boff[c],  lds + 24576 + 8192, c*512 + wb);
    asm volatile("s_waitcnt vmcnt(6)" ::: "memory");
    __builtin_amdgcn_s_barrier();
    asm volatile("" ::: "memory");

    int cur = 0;
    #pragma unroll 1
    for (int T = 0; T < 16; T++) {
        f16* buf        = lds + cur*24576;
        const int nxt   = cur ? cur - 1 : 2;
        f16* nbuf       = lds + nxt*24576;
        const bool st   = (T < 14);
        const int  kt2  = (T + 2) * 64;

        if (st) {
            #pragma unroll
            for (int c = 0; c < 2; c++)
                gl_lds16(Ag + kt2 + aoff[c], nbuf, c*512 + wb);
        }
        f16_8 af[4][2], bf[2][2];
        #pragma unroll
        for (int mi = 0; mi < 4; mi++)
            #pragma unroll
            for (int kk = 0; kk < 2; kk++)
                af[mi][kk] = *(const f16_8*)&buf[fa[mi][kk]];
        #pragma unroll
        for (int ni = 0; ni < 2; ni++)
            #pragma unroll
            for (int kk = 0; kk < 2; kk++)
                bf[ni][kk] = *(const f16_8*)&buf[8192 + fb[ni][kk]];
        asm volatile("" ::: "memory");
        __builtin_amdgcn_s_barrier();
        asm volatile("" ::: "memory");
        __builtin_amdgcn_s_setprio(1);
        #pragma unroll
        for (int kk = 0; kk < 2; kk++)
            #pragma unroll
            for (int mi = 0; mi < 4; mi++)
                #pragma unroll
                for (int ni = 0; ni < 2; ni++)
                    acc[mi][ni] = MFMA32(af[mi][kk], bf[ni][kk], acc[mi][ni]);
        __builtin_amdgcn_s_setprio(0);
        asm volatile("" ::: "memory");
        __builtin_amdgcn_s_barrier();
        asm volatile("" ::: "memory");

        if (st) {
            #pragma unroll
            for (int c = 0; c < 4; c++)
                gl_lds16(Bg + kt2 + boff[c], nbuf + 8192, c*512 + wb);
        }
        #pragma unroll
        for (int ni = 0; ni < 2; ni++)
            #pragma unroll
            for (int kk = 0; kk < 2; kk++)
                bf[ni][kk] = *(const f16_8*)&buf[8192 + fb[2 + ni][kk]];
        asm volatile("" ::: "memory");
        __builtin_amdgcn_s_barrier();
        asm volatile("" ::: "memory");
        __builtin_amdgcn_s_setprio(1);
        #pragma unroll
        for (int kk = 0; kk < 2; kk++)
            #pragma unroll
            for (int mi = 0; mi < 4; mi++)
                #pragma unroll
                for (int ni = 0; ni < 2; ni++)
                    acc[mi][2 + ni] = MFMA32(af[mi][kk], bf[ni][kk], acc[mi][2 + ni]);
        __builtin_amdgcn_s_setprio(0);
        if (T < 14)       asm volatile("s_waitcnt vmcnt(6)" ::: "memory");
        else if (T == 14) asm volatile("s_waitcnt vmcnt(0)" ::: "memory");
        __builtin_amdgcn_s_barrier();
        asm volatile("" ::: "memory");

        cur = (cur >= 2) ? 0 : cur + 1;
    }

    #pragma unroll
    for (int mi = 0; mi < 4; mi++)
    #pragma unroll
    for (int ni = 0; ni < 4; ni++)
    #pragma unroll
    for (int r = 0; r < 4; r++) {
        int m = m0 + wr*64 + mi*16 + quad*4 + r;
        int n = n0 + wc*64 + ni*16 + l15;
        Out[(size_t)m*1024 + n] = acc[mi][ni][r] + bias[n];
    }
}

// ---------------------------------------------------------------------------
extern "C" void kernel_launch(void* const* d_in, const int* in_sizes, int n_in,
                              void* d_out, int out_size, void* d_ws, size_t ws_size,
                              hipStream_t stream) {
    const float* x      = (const float*)d_in[0];
    const float* W_attn = (const float*)d_in[1];
    const float* b_attn = (const float*)d_in[2];
    const float* W_proj = (const float*)d_in[3];
    const float* b_proj = (const float*)d_in[4];
    float* out = (float*)d_out;

    const size_t per = (size_t)B_ * H_ * S_ * HD_;   // 8,388,608 elems
    f16* Yb  = (f16*)d_ws;        // [0, per)      attn output
    f16* Wta = Yb;                //   alias: W_attn^T f16 (dead before Yb written)
    f16* Qb  = Yb + per;          // [per, 2per)
    f16* Kb  = Qb + per;          // [2per, 3per)
    f16* Vt  = Kb + per;          // [3per, 4per)  total 67.1 MB
    f16* Xh  = (f16*)d_out;       //   scratch: d_out dead until proj_gemm

    // big-ws mode: Wtp gets its own 2 MB past the 4 buffers -> W_proj
    // transpose folds into prep (one fewer launch).  Fallback = r12 layout.
    const bool big = ws_size >= (4*per + (size_t)D_*D_) * sizeof(f16);
    f16* Wtp = big ? (Vt + per) : Qb;

    prep     <<<4096 + 768 + (big ? 256 : 0), 256, 0, stream>>>(
                 x, Xh, W_attn, Wta, W_proj, Wtp);
    qkv_gemm <<<dim3(64, 12), 512, 0, stream>>>(Xh, Wta, b_attn, Qb, Kb, Vt);
    attn     <<<dim3(64, 16), 256, 0, stream>>>(Qb, Kb, Vt, Yb);
    if (!big)
        trans_w<<<dim3(16, 16), 256, 0, stream>>>(W_proj, Wtp, D_);
    proj_gemm<<<dim3(64, 4),  512, 0, stream>>>(Yb, Wtp, b_proj, out);
}

// Round 18
// 247.469 us; speedup vs baseline: 1.0538x; 1.0538x over previous
//
#include <hip/hip_runtime.h>

#define B_  4
#define S_  2048
#define D_  1024
#define H_  16
#define HD_ 64
#define BS_ (B_*S_)   // 8192

typedef _Float16 f16;
typedef _Float16 f16_8 __attribute__((ext_vector_type(8)));
typedef _Float16 f16_4 __attribute__((ext_vector_type(4)));
typedef float    f32_4 __attribute__((ext_vector_type(4)));
typedef unsigned int u32;

#define MFMA32(a,b,c) __builtin_amdgcn_mfma_f32_16x16x32_f16(a, b, c, 0, 0, 0)
#define MFMA16(a,b,c) __builtin_amdgcn_mfma_f32_16x16x16f16(a, b, c, 0, 0, 0)
#define NEG_INF (-__builtin_inff())

// async global->LDS, 16B per lane. chunk_base in lane units (16B each),
// must be wave-uniform; HW adds lane*16B.
__device__ inline void gl_lds16(const f16* g, f16* lds_base, int chunk_base) {
    __builtin_amdgcn_global_load_lds(
        (const __attribute__((address_space(1))) u32*)g,
        (__attribute__((address_space(3))) u32*)(lds_base + (size_t)chunk_base * 8),
        16, 0, 0);
}

// ---------------------------------------------------------------------------
// prep: blocks [0,4096) convert X fp32->f16; blocks [4096,4864) transpose
// W_attn fp32 [1024][3072] -> Wta f16 [3072][1024]; blocks [4864,5120)
// (big-ws mode only) transpose W_proj -> Wtp.   [validated r14]
// ---------------------------------------------------------------------------
__global__ __launch_bounds__(256) void prep(
    const float* __restrict__ X,  f16* __restrict__ Xh,
    const float* __restrict__ Wa, f16* __restrict__ Wta,
    const float* __restrict__ Wp, f16* __restrict__ Wtp)
{
    __shared__ f16 T[64][72];
    const int t = threadIdx.x;
    const int bid = blockIdx.x;
    if (bid < 4096) {
        const size_t i = ((size_t)bid * 256 + t) * 8;
        float4 a = *(const float4*)&X[i];
        float4 b = *(const float4*)&X[i + 4];
        f16 h[8] = {(f16)a.x,(f16)a.y,(f16)a.z,(f16)a.w,
                    (f16)b.x,(f16)b.y,(f16)b.z,(f16)b.w};
        *(uint4*)&Xh[i] = *(const uint4*)h;
        return;
    }
    int n0, k0, ncols;
    const float* Wsrc;
    f16* Wdst;
    if (bid < 4864) {
        const int idx = bid - 4096;
        n0 = (idx % 48) * 64; k0 = (idx / 48) * 64;
        ncols = 3072; Wsrc = Wa; Wdst = Wta;
    } else {
        const int idx = bid - 4864;
        n0 = (idx % 16) * 64; k0 = (idx / 16) * 64;
        ncols = 1024; Wsrc = Wp; Wdst = Wtp;
    }
    const int nl4 = (t & 15) * 4;
    #pragma unroll
    for (int r = 0; r < 4; r++) {
        const int kl = (t >> 4) + r * 16;
        float4 v = *(const float4*)&Wsrc[(size_t)(k0 + kl) * ncols + n0 + nl4];
        T[nl4 + 0][kl] = (f16)v.x;
        T[nl4 + 1][kl] = (f16)v.y;
        T[nl4 + 2][kl] = (f16)v.z;
        T[nl4 + 3][kl] = (f16)v.w;
    }
    __syncthreads();
    const int nr = t >> 2, kc = (t & 3) * 16;
    *(uint4*)&Wdst[(size_t)(n0 + nr) * 1024 + k0 + kc]     = *(uint4*)&T[nr][kc];
    *(uint4*)&Wdst[(size_t)(n0 + nr) * 1024 + k0 + kc + 8] = *(uint4*)&T[nr][kc + 8];
}

// ---------------------------------------------------------------------------
// Transpose + convert: W [1024][ncols] fp32 -> Wt [ncols][1024] f16
// (fallback path only: runs after attn, Wtp aliases the dead Q buffer)
// ---------------------------------------------------------------------------
__global__ __launch_bounds__(256) void trans_w(
    const float* __restrict__ W, f16* __restrict__ Wt, int ncols)
{
    __shared__ f16 T[64][72];
    const int t = threadIdx.x;
    const int n0 = blockIdx.x * 64, k0 = blockIdx.y * 64;
    const int nl4 = (t & 15) * 4;
    #pragma unroll
    for (int r = 0; r < 4; r++) {
        const int kl = (t >> 4) + r * 16;
        float4 v = *(const float4*)&W[(size_t)(k0 + kl) * ncols + n0 + nl4];
        T[nl4 + 0][kl] = (f16)v.x;
        T[nl4 + 1][kl] = (f16)v.y;
        T[nl4 + 2][kl] = (f16)v.z;
        T[nl4 + 3][kl] = (f16)v.w;
    }
    __syncthreads();
    const int nr = t >> 2, kc = (t & 3) * 16;
    *(uint4*)&Wt[(size_t)(n0 + nr) * 1024 + k0 + kc]     = *(uint4*)&T[nr][kc];
    *(uint4*)&Wt[(size_t)(n0 + nr) * 1024 + k0 + kc + 8] = *(uint4*)&T[nr][kc + 8];
}

// ---------------------------------------------------------------------------
// GEMM1: qkv = x @ W_attn + b_attn.  Deep-pipeline K-loop (validated
// r5/r10); r11 coalesced Q/K epilogue (validated r12: left top-5).
// ---------------------------------------------------------------------------
__global__ __launch_bounds__(512, 2) void qkv_gemm(
    const f16*   __restrict__ Xh,    // [8192,1024] f16
    const f16*   __restrict__ Wta,   // [3072,1024] f16 (pre-transposed)
    const float* __restrict__ bias,  // [3072]
    f16* __restrict__ Qb, f16* __restrict__ Kb, f16* __restrict__ Vt)
{
    __shared__ f16 lds[73728];   // 3 x (A 8192 + B 16384) f16 = 144 KB

    const int t    = threadIdx.x;
    const int lane = t & 63;
    const int w    = t >> 6;                 // 0..7
    const int quad = lane >> 4, l15 = lane & 15;
    const int wr = w >> 2, wc = w & 3;       // 2 x 4 wave grid
    const int m0 = blockIdx.x * 128;         // m fastest -> X strips XCD-local
    const int n0 = blockIdx.y * 256;
    const int wb = t & 448;                  // wave-uniform chunk base

    int aoff[2], boff[4];
    #pragma unroll
    for (int c = 0; c < 2; c++) {
        const int i = c*512 + t, row = i >> 3, sl = i & 7;
        aoff[c] = row*1024 + ((sl ^ (row & 7)) << 3);
    }
    #pragma unroll
    for (int c = 0; c < 4; c++) {
        const int i = c*512 + t, row = i >> 3, sl = i & 7;
        boff[c] = row*1024 + ((sl ^ (row & 7)) << 3);
    }
    int fa[4][2], fb[4][2];
    #pragma unroll
    for (int mi = 0; mi < 4; mi++)
        #pragma unroll
        for (int kk = 0; kk < 2; kk++)
            fa[mi][kk] = (wr*64 + mi*16 + l15)*64 + (((kk*4 + quad) ^ (l15 & 7)) << 3);
    #pragma unroll
    for (int ni = 0; ni < 4; ni++)
        #pragma unroll
        for (int kk = 0; kk < 2; kk++)
            fb[ni][kk] = (wc*64 + ni*16 + l15)*64 + (((kk*4 + quad) ^ (l15 & 7)) << 3);

    const f16* Ag = Xh  + (size_t)m0 * 1024;
    const f16* Bg = Wta + (size_t)n0 * 1024;

    f32_4 acc[4][4] = {};

    #pragma unroll
    for (int c = 0; c < 2; c++) gl_lds16(Ag + aoff[c],       lds,                c*512 + wb);
    #pragma unroll
    for (int c = 0; c < 4; c++) gl_lds16(Bg + boff[c],       lds + 8192,         c*512 + wb);
    #pragma unroll
    for (int c = 0; c < 2; c++) gl_lds16(Ag + 64 + aoff[c],  lds + 24576,        c*512 + wb);
    #pragma unroll
    for (int c = 0; c < 4; c++) gl_lds16(Bg + 64 + boff[c],  lds + 24576 + 8192, c*512 + wb);
    asm volatile("s_waitcnt vmcnt(6)" ::: "memory");
    __builtin_amdgcn_s_barrier();
    asm volatile("" ::: "memory");

    int cur = 0;
    #pragma unroll 1
    for (int T = 0; T < 16; T++) {
        f16* buf        = lds + cur*24576;
        const int nxt   = cur ? cur - 1 : 2;
        f16* nbuf       = lds + nxt*24576;
        const bool st   = (T < 14);
        const int  kt2  = (T + 2) * 64;

        if (st) {
            #pragma unroll
            for (int c = 0; c < 2; c++)
                gl_lds16(Ag + kt2 + aoff[c], nbuf, c*512 + wb);
        }
        f16_8 af[4][2], bf[2][2];
        #pragma unroll
        for (int mi = 0; mi < 4; mi++)
            #pragma unroll
            for (int kk = 0; kk < 2; kk++)
                af[mi][kk] = *(const f16_8*)&buf[fa[mi][kk]];
        #pragma unroll
        for (int ni = 0; ni < 2; ni++)
            #pragma unroll
            for (int kk = 0; kk < 2; kk++)
                bf[ni][kk] = *(const f16_8*)&buf[8192 + fb[ni][kk]];
        asm volatile("" ::: "memory");
        __builtin_amdgcn_s_barrier();
        asm volatile("" ::: "memory");
        __builtin_amdgcn_s_setprio(1);
        #pragma unroll
        for (int kk = 0; kk < 2; kk++)
            #pragma unroll
            for (int mi = 0; mi < 4; mi++)
                #pragma unroll
                for (int ni = 0; ni < 2; ni++)
                    acc[mi][ni] = MFMA32(af[mi][kk], bf[ni][kk], acc[mi][ni]);
        __builtin_amdgcn_s_setprio(0);
        asm volatile("" ::: "memory");
        __builtin_amdgcn_s_barrier();
        asm volatile("" ::: "memory");

        if (st) {
            #pragma unroll
            for (int c = 0; c < 4; c++)
                gl_lds16(Bg + kt2 + boff[c], nbuf + 8192, c*512 + wb);
        }
        #pragma unroll
        for (int ni = 0; ni < 2; ni++)
            #pragma unroll
            for (int kk = 0; kk < 2; kk++)
                bf[ni][kk] = *(const f16_8*)&buf[8192 + fb[2 + ni][kk]];
        asm volatile("" ::: "memory");
        __builtin_amdgcn_s_barrier();
        asm volatile("" ::: "memory");
        __builtin_amdgcn_s_setprio(1);
        #pragma unroll
        for (int kk = 0; kk < 2; kk++)
            #pragma unroll
            for (int mi = 0; mi < 4; mi++)
                #pragma unroll
                for (int ni = 0; ni < 2; ni++)
                    acc[mi][2 + ni] = MFMA32(af[mi][kk], bf[ni][kk], acc[mi][2 + ni]);
        __builtin_amdgcn_s_setprio(0);
        if (T < 14)       asm volatile("s_waitcnt vmcnt(6)" ::: "memory");
        else if (T == 14) asm volatile("s_waitcnt vmcnt(0)" ::: "memory");
        __builtin_amdgcn_s_barrier();
        asm volatile("" ::: "memory");

        cur = (cur >= 2) ? 0 : cur + 1;
    }

    const int which = n0 >> 10;      // 0=Q 1=K 2=V
    float bcol[4];
    #pragma unroll
    for (int ni = 0; ni < 4; ni++)
        bcol[ni] = bias[n0 + wc*64 + ni*16 + l15];

    if (which < 2) {
        f16* dstB = (which == 0) ? Qb : Kb;
        const float sc = (which == 0) ? 0.125f * 1.44269504f : 1.0f;
        f16* Ct2 = lds;              // [128][264] f16 = 67.6 KB, buffers dead
        #pragma unroll
        for (int mi = 0; mi < 4; mi++)
        #pragma unroll
        for (int ni = 0; ni < 4; ni++)
        #pragma unroll
        for (int r = 0; r < 4; r++) {
            int ml = wr*64 + mi*16 + quad*4 + r;
            int nl = wc*64 + ni*16 + l15;
            Ct2[ml*264 + nl] = (f16)((acc[mi][ni][r] + bcol[ni]) * sc);
        }
        __syncthreads();
        const int b  = m0 >> 11, s0 = m0 & 2047;
        const int h0 = (n0 & 1023) >> 6;
        #pragma unroll
        for (int c = 0; c < 8; c++) {
            const int i   = c*512 + t;
            const int row = i >> 5, j = (i >> 3) & 3, k = i & 7;
            f16* dst = dstB + ((size_t)(b*16 + h0 + j)*2048 + s0 + row)*64 + k*8;
            *(uint4*)dst = *(const uint4*)&Ct2[row*264 + j*64 + k*8];
        }
    } else {
        f16* Ct = lds;               // [256][136] f16, buffers dead
        #pragma unroll
        for (int mi = 0; mi < 4; mi++)
        #pragma unroll
        for (int ni = 0; ni < 4; ni++)
        #pragma unroll
        for (int r = 0; r < 4; r++) {
            int nl = wc*64 + ni*16 + l15;
            int ml = wr*64 + mi*16 + quad*4 + r;
            Ct[nl*136 + ml] = (f16)(acc[mi][ni][r] + bcol[ni]);
        }
        __syncthreads();
        const int row = t >> 1, half = t & 1;
        const int nv = (n0 & 1023) + row;
        const int h = nv >> 6, hd = nv & 63;
        const int b = m0 >> 11;
        const int s0 = (m0 & 2047) + half*64;
        f16* dst = Vt + ((size_t)(b*16 + h)*64 + hd)*2048 + s0;
        #pragma unroll
        for (int j = 0; j < 8; j++)
            *(uint4*)&dst[j*8] = *(uint4*)&Ct[row*136 + half*64 + j*8];
    }
}

// ---------------------------------------------------------------------------
// Flash causal attention — r12-EXACT revert (best measured: 72 us).
// r13/r14's 3-deep ring raised VGPR 64->88 and LDS 32->48KB, dropping
// blocks/CU and regressing to 82 us.  In this latency-bound kernel,
// resident-block count dominates prefetch depth.
// One strip per block (4 waves), grid (64,16) longest-first, 32KB
// double-buffer, counted vmcnt(4), XOR swizzle, setprio.
// ---------------------------------------------------------------------------
__global__ __launch_bounds__(256, 4) void attn(
    const f16* __restrict__ Qb,
    const f16* __restrict__ Kb,
    const f16* __restrict__ Vt,     // [bh][hd][s]
    f16* __restrict__ Y)            // [8192,1024]
{
    __shared__ f16 lds[16384];      // 2 buf x (K[64][64] + V[64][64]) = 32 KB

    const int t    = threadIdx.x;
    const int w    = t >> 6;        // 0..3
    const int lane = t & 63;
    const int quad = lane >> 4, l15 = lane & 15;
    const int bh   = blockIdx.x;    // bh fastest -> same XCD per bh
    const int b    = bh >> 4, h = bh & 15;
    const int strip = 15 - (int)blockIdx.y;   // longest first
    const int qw   = strip*128 + w*32;
    const int NT   = 2*strip + 2;

    const f16* qh = Qb + (size_t)bh * S_ * 64;
    const f16* kh = Kb + (size_t)bh * S_ * 64;
    const f16* vt = Vt + (size_t)bh * 64 * S_;

    int srcK[2], srcV[2];
    #pragma unroll
    for (int c = 0; c < 2; c++) {
        const int i = c*256 + t, row = i >> 3, sl = i & 7;
        const int sw = ((sl ^ (row & 7)) << 3);
        srcK[c] = row*64   + sw;
        srcV[c] = row*2048 + sw;
    }
    const int wbase = t & 192;      // wave-uniform dest base
    const int l7    = l15 & 7;
    const f16_4 ones = {(f16)1,(f16)1,(f16)1,(f16)1};

    f16_8 qa[2][2];
    #pragma unroll
    for (int rt = 0; rt < 2; rt++)
        #pragma unroll
        for (int c = 0; c < 2; c++)
            qa[rt][c] = *(const f16_8*)&qh[(size_t)(qw + rt*16 + l15)*64 + c*32 + quad*8];

    f32_4 o[2][4] = {};
    f32_4 lacc[2] = {};

    #pragma unroll
    for (int c = 0; c < 2; c++) {
        gl_lds16(kh + srcK[c], lds,        c*256 + wbase);
        gl_lds16(vt + srcV[c], lds + 4096, c*256 + wbase);
    }

    #pragma unroll 1
    for (int kt = 0; kt < NT; kt++) {
        const int kbase = kt * 64;
        f16* Ks = lds + (kt & 1) * 8192;
        f16* Vs = Ks + 4096;

        if (kt + 1 < NT) {
            const int nb = kbase + 64;
            f16* nK = lds + ((kt + 1) & 1) * 8192;
            #pragma unroll
            for (int c = 0; c < 2; c++) {
                gl_lds16(kh + (size_t)nb*64 + srcK[c], nK,        c*256 + wbase);
                gl_lds16(vt + nb + srcV[c],            nK + 4096, c*256 + wbase);
            }
            asm volatile("s_waitcnt vmcnt(4)" ::: "memory");
        } else {
            asm volatile("s_waitcnt vmcnt(0)" ::: "memory");
        }
        __builtin_amdgcn_s_barrier();
        asm volatile("" ::: "memory");

        if (kbase <= qw + 31) {      // wave-uniform
            f16_8 kb[4][2];
            #pragma unroll
            for (int sub = 0; sub < 4; sub++)
                #pragma unroll
                for (int c = 0; c < 2; c++)
                    kb[sub][c] = *(const f16_8*)
                        &Ks[(sub*16 + l15)*64 + (((c*4 + quad) ^ l7) << 3)];
            f32_4 st[2][4];
            __builtin_amdgcn_s_setprio(1);
            #pragma unroll
            for (int rt = 0; rt < 2; rt++)
                #pragma unroll
                for (int sub = 0; sub < 4; sub++) {
                    f32_4 a = {};
                    a = MFMA32(kb[sub][0], qa[rt][0], a);
                    a = MFMA32(kb[sub][1], qa[rt][1], a);
                    st[rt][sub] = a;
                }
            __builtin_amdgcn_s_setprio(0);

            const bool masked = (kbase + 63 > qw);
            f16_4 pt[2][4];
            #pragma unroll
            for (int rt = 0; rt < 2; rt++)
            #pragma unroll
            for (int sub = 0; sub < 4; sub++) {
                const int qrow = qw + rt*16 + l15;
                f16_4 p;
                #pragma unroll
                for (int r = 0; r < 4; r++) {
                    float x = st[rt][sub][r];
                    if (masked) {
                        int key = kbase + sub*16 + quad*4 + r;
                        x = (key <= qrow) ? x : NEG_INF;
                    }
                    p[r] = (f16)__builtin_amdgcn_exp2f(x);
                }
                pt[rt][sub] = p;
            }

            #pragma unroll
            for (int rt = 0; rt < 2; rt++) {
                f16_4 ps = (pt[rt][0] + pt[rt][1]) + (pt[rt][2] + pt[rt][3]);
                lacc[rt] = MFMA16(ps, ones, lacc[rt]);
            }

            __builtin_amdgcn_s_setprio(1);
            #pragma unroll
            for (int sub = 0; sub < 4; sub++) {
                f16_4 vb[4];
                #pragma unroll
                for (int tt = 0; tt < 4; tt++)
                    vb[tt] = *(const f16_4*)
                        &Vs[(tt*16 + l15)*64 +
                            ((((sub*2 + (quad >> 1)) ^ l7) << 3) + (quad & 1)*4)];
                #pragma unroll
                for (int rt = 0; rt < 2; rt++)
                    #pragma unroll
                    for (int tt = 0; tt < 4; tt++)
                        o[rt][tt] = MFMA16(pt[rt][sub], vb[tt], o[rt][tt]);
            }
            __builtin_amdgcn_s_setprio(0);
        }
        asm volatile("" ::: "memory");
        __builtin_amdgcn_s_barrier();
        asm volatile("" ::: "memory");
    }

    #pragma unroll
    for (int rt = 0; rt < 2; rt++)
    #pragma unroll
    for (int r = 0; r < 4; r++) {
        float inv = 1.0f / lacc[rt][r];
        int srw = qw + rt*16 + quad*4 + r;
        #pragma unroll
        for (int tt = 0; tt < 4; tt++)
            Y[(size_t)(b*S_ + srw)*1024 + h*64 + tt*16 + l15] =
                (f16)(o[rt][tt][r] * inv);
    }
}

// ---------------------------------------------------------------------------
// GEMM2: out = y @ W_proj + b_proj.  r11-validated qkv K-loop clone.
// Grid (64,4) = 256 blocks = exactly 1/CU.
// ---------------------------------------------------------------------------
__global__ __launch_bounds__(512, 2) void proj_gemm(
    const f16* __restrict__ Yb,     // [8192,1024]
    const f16* __restrict__ Wtp,    // [1024,1024] (pre-transposed)
    const float* __restrict__ bias, // [1024]
    float* __restrict__ Out)        // [8192,1024] fp32
{
    __shared__ f16 lds[73728];   // 144 KB

    const int t    = threadIdx.x;
    const int lane = t & 63;
    const int w    = t >> 6;
    const int quad = lane >> 4, l15 = lane & 15;
    const int wr = w >> 2, wc = w & 3;
    const int m0 = blockIdx.x * 128;
    const int n0 = blockIdx.y * 256;
    const int wb = t & 448;

    int aoff[2], boff[4];
    #pragma unroll
    for (int c = 0; c < 2; c++) {
        const int i = c*512 + t, row = i >> 3, sl = i & 7;
        aoff[c] = row*1024 + ((sl ^ (row & 7)) << 3);
    }
    #pragma unroll
    for (int c = 0; c < 4; c++) {
        const int i = c*512 + t, row = i >> 3, sl = i & 7;
        boff[c] = row*1024 + ((sl ^ (row & 7)) << 3);
    }
    int fa[4][2], fb[4][2];
    #pragma unroll
    for (int mi = 0; mi < 4; mi++)
        #pragma unroll
        for (int kk = 0; kk < 2; kk++)
            fa[mi][kk] = (wr*64 + mi*16 + l15)*64 + (((kk*4 + quad) ^ (l15 & 7)) << 3);
    #pragma unroll
    for (int ni = 0; ni < 4; ni++)
        #pragma unroll
        for (int kk = 0; kk < 2; kk++)
            fb[ni][kk] = (wc*64 + ni*16 + l15)*64 + (((kk*4 + quad) ^ (l15 & 7)) << 3);

    const f16* Ag = Yb  + (size_t)m0 * 1024;
    const f16* Bg = Wtp + (size_t)n0 * 1024;

    f32_4 acc[4][4] = {};

    #pragma unroll
    for (int c = 0; c < 2; c++) gl_lds16(Ag + aoff[c],       lds,                c*512 + wb);
    #pragma unroll
    for (int c = 0; c < 4; c++) gl_lds16(Bg + boff[c],       lds + 8192,         c*512 + wb);
    #pragma unroll
    for (int c = 0; c < 2; c++) gl_lds16(Ag + 64 + aoff[c],  lds + 24576,        c*512 + wb);
    #pragma unroll
    for (int c = 0; c < 4; c++) gl_lds16(Bg + 64 + boff[c],  lds + 24576 + 8192, c*512 + wb);
    asm volatile("s_waitcnt vmcnt(6)" ::: "memory");
    __builtin_amdgcn_s_barrier();
    asm volatile("" ::: "memory");

    int cur = 0;
    #pragma unroll 1
    for (int T = 0; T < 16; T++) {
        f16* buf        = lds + cur*24576;
        const int nxt   = cur ? cur - 1 : 2;
        f16* nbuf       = lds + nxt*24576;
        const bool st   = (T < 14);
        const int  kt2  = (T + 2) * 64;

        if (st) {
            #pragma unroll
            for (int c = 0; c < 2; c++)
                gl_lds16(Ag + kt2 + aoff[c], nbuf, c*512 + wb);
        }
        f16_8 af[4][2], bf[2][2];
        #pragma unroll
        for (int mi = 0; mi < 4; mi++)
            #pragma unroll
            for (int kk = 0; kk < 2; kk++)
                af[mi][kk] = *(const f16_8*)&buf[fa[mi][kk]];
        #pragma unroll
        for (int ni = 0; ni < 2; ni++)
            #pragma unroll
            for (int kk = 0; kk < 2; kk++)
                bf[ni][kk] = *(const f16_8*)&buf[8192 + fb[ni][kk]];
        asm volatile("" ::: "memory");
        __builtin_amdgcn_s_barrier();
        asm volatile("" ::: "memory");
        __builtin_amdgcn_s_setprio(1);
        #pragma unroll
        for (int kk = 0; kk < 2; kk++)
            #pragma unroll
            for (int mi = 0; mi < 4; mi++)
                #pragma unroll
                for (int ni = 0; ni < 2; ni++)
                    acc[mi][ni] = MFMA32(af[mi][kk], bf[ni][kk], acc[mi][ni]);
        __builtin_amdgcn_s_setprio(0);
        asm volatile("" ::: "memory");
        __builtin_amdgcn_s_barrier();
        asm volatile("" ::: "memory");

        if (st) {
            #pragma unroll
            for (int c = 0; c < 4; c++)
                gl_lds16(Bg + kt2 + boff[c], nbuf + 8192, c*512 + wb);
        }
        #pragma unroll
        for (int ni = 0; ni < 2; ni++)
            #pragma unroll
            for (int kk = 0; kk < 2; kk++)
                bf[ni][kk] = *(const f16_8*)&buf[8192 + fb[2 + ni][kk]];
        asm volatile("" ::: "memory");
        __builtin_amdgcn_s_barrier();
        asm volatile("" ::: "memory");
        __builtin_amdgcn_s_setprio(1);
        #pragma unroll
        for (int kk = 0; kk < 2; kk++)
            #pragma unroll
            for (int mi = 0; mi < 4; mi++)
                #pragma unroll
                for (int ni = 0; ni < 2; ni++)
                    acc[mi][2 + ni] = MFMA32(af[mi][kk], bf[ni][kk], acc[mi][2 + ni]);
        __builtin_amdgcn_s_setprio(0);
        if (T < 14)       asm volatile("s_waitcnt vmcnt(6)" ::: "memory");
        else if (T == 14) asm volatile("s_waitcnt vmcnt(0)" ::: "memory");
        __builtin_amdgcn_s_barrier();
        asm volatile("" ::: "memory");

        cur = (cur >= 2) ? 0 : cur + 1;
    }

    #pragma unroll
    for (int mi = 0; mi < 4; mi++)
    #pragma unroll
    for (int ni = 0; ni < 4; ni++)
    #pragma unroll
    for (int r = 0; r < 4; r++) {
        int m = m0 + wr*64 + mi*16 + quad*4 + r;
        int n = n0 + wc*64 + ni*16 + l15;
        Out[(size_t)m*1024 + n] = acc[mi][ni][r] + bias[n];
    }
}

// ---------------------------------------------------------------------------
extern "C" void kernel_launch(void* const* d_in, const int* in_sizes, int n_in,
                              void* d_out, int out_size, void* d_ws, size_t ws_size,
                              hipStream_t stream) {
    const float* x      = (const float*)d_in[0];
    const float* W_attn = (const float*)d_in[1];
    const float* b_attn = (const float*)d_in[2];
    const float* W_proj = (const float*)d_in[3];
    const float* b_proj = (const float*)d_in[4];
    float* out = (float*)d_out;

    const size_t per = (size_t)B_ * H_ * S_ * HD_;   // 8,388,608 elems
    f16* Yb  = (f16*)d_ws;        // [0, per)      attn output
    f16* Wta = Yb;                //   alias: W_attn^T f16 (dead before Yb written)
    f16* Qb  = Yb + per;          // [per, 2per)
    f16* Kb  = Qb + per;          // [2per, 3per)
    f16* Vt  = Kb + per;          // [3per, 4per)  total 67.1 MB
    f16* Xh  = (f16*)d_out;       //   scratch: d_out dead until proj_gemm

    // big-ws mode: Wtp gets its own 2 MB past the 4 buffers -> W_proj
    // transpose folds into prep (one fewer launch).  Fallback = r12 layout.
    const bool big = ws_size >= (4*per + (size_t)D_*D_) * sizeof(f16);
    f16* Wtp = big ? (Vt + per) : Qb;

    prep     <<<4096 + 768 + (big ? 256 : 0), 256, 0, stream>>>(
                 x, Xh, W_attn, Wta, W_proj, Wtp);
    qkv_gemm <<<dim3(64, 12), 512, 0, stream>>>(Xh, Wta, b_attn, Qb, Kb, Vt);
    attn     <<<dim3(64, 16), 256, 0, stream>>>(Qb, Kb, Vt, Yb);
    if (!big)
        trans_w<<<dim3(16, 16), 256, 0, stream>>>(W_proj, Wtp, D_);
    proj_gemm<<<dim3(64, 4),  512, 0, stream>>>(Yb, Wtp, b_proj, out);
}